// Round 2
// 1684.730 us; speedup vs baseline: 1.1430x; 1.1430x over previous
//
#include <hip/hip_runtime.h>
#include <math.h>

#define K_     191
#define LD     192
#define N_     147456
#define MSUB   16
#define NT     15
#define TRI_N  18336   // 191*192/2
#define SMEM_SZ ((TRI_N + 192 + 192 + 1056) * 8)
// k_sub dynamic LDS: 6880 doubles + 32 ints + 18336 floats
#define SMEM2_SZ (6880 * 8 + 32 * 4 + TRI_N * 4)

// k_rr geometry: 64-wide col blocks, 6 pairs, 128 K-splits
#define NPAIR  6
#define NSPLIT 128
#define CHUNK  (N_ / NSPLIT)   // 1152
#define RSTEP  32

// db5 decomposition filters (pywt convention), f32 as in reference
__constant__ float c_lo[10] = {
  0.003335725285001549f, -0.012580751999015526f, -0.006241490213011705f,
  0.07757149384006515f,  -0.03224486958502952f, -0.24229488706619015f,
  0.13842814590110342f,   0.7243085284385744f,   0.6038292697974729f,
  0.160102397974125f };
__constant__ float c_hi[10] = {
  0.160102397974125f,    -0.6038292697974729f,   0.7243085284385744f,
 -0.13842814590110342f,  -0.24229488706619015f,  0.03224486958502952f,
  0.07757149384006515f,   0.006241490213011705f,-0.012580751999015526f,
 -0.003335725285001549f };

// ---------------- column sums of x (f64), for the regression mean ----------
__global__ __launch_bounds__(256) void k_colsum(const float* __restrict__ x,
                                                double* __restrict__ m)
{
  int t = threadIdx.x;
  long base = (long)blockIdx.x * 512;
  if (t < K_) {
    double s = 0.0;
    const float* p = x + base * K_ + t;
    for (int r = 0; r < 512; ++r) s += (double)p[(long)r * K_];
    atomicAdd(&m[t], s);
  }
}

// ---------------- rr = x^T x, register-tiled VALU f64, split-K atomics -----
// Block computes a 64x64 output tile (pair bi<=bj of 64-col blocks) over a
// CHUNK of rows. 256 threads, each owns a 4x4 register sub-tile with rows
// ty+16v, cols tx+16u (spread layout: A-reads broadcast, B-reads stride-8B
// conflict-free). x staged to LDS as f64 (convert once on store).
__global__ __launch_bounds__(256, 3) void k_rr(const float* __restrict__ x,
                                               double* __restrict__ rrg)
{
  __shared__ double Asd[RSTEP][64];
  __shared__ double Bsd[RSTEP][64];

  const int bid   = blockIdx.x;
  const int split = bid & (NSPLIT - 1);
  const int pair  = bid >> 7;
  const int BI[6] = {0, 0, 0, 1, 1, 2};
  const int BJ[6] = {0, 1, 2, 1, 2, 2};
  const int bi = BI[pair], bj = BJ[pair];
  const int ca = bi * 64, cb = bj * 64;

  const int t  = threadIdx.x;
  const int tx = t & 15, ty = t >> 4;
  const long n0 = (long)split * CHUNK;

  double acc[4][4];
  #pragma unroll
  for (int v = 0; v < 4; ++v)
    #pragma unroll
    for (int u = 0; u < 4; ++u) acc[v][u] = 0.0;

  for (int r0 = 0; r0 < CHUNK; r0 += RSTEP) {
    // stage RSTEP x 64 of each col-block as f64
    for (int s = t; s < RSTEP * 16; s += 256) {
      int row = s >> 4, g = s & 15;
      long gr = (n0 + r0 + row) * (long)K_;
      int c4a = ca + g * 4, c4b = cb + g * 4;
      #pragma unroll
      for (int e = 0; e < 4; ++e) {
        Asd[row][g * 4 + e] = (c4a + e < K_) ? (double)x[gr + c4a + e] : 0.0;
        Bsd[row][g * 4 + e] = (c4b + e < K_) ? (double)x[gr + c4b + e] : 0.0;
      }
    }
    __syncthreads();
    #pragma unroll 4
    for (int k = 0; k < RSTEP; ++k) {
      double a0 = Asd[k][ty],      a1 = Asd[k][ty + 16];
      double a2 = Asd[k][ty + 32], a3 = Asd[k][ty + 48];
      double b0 = Bsd[k][tx],      b1 = Bsd[k][tx + 16];
      double b2 = Bsd[k][tx + 32], b3 = Bsd[k][tx + 48];
      acc[0][0] += a0 * b0; acc[0][1] += a0 * b1; acc[0][2] += a0 * b2; acc[0][3] += a0 * b3;
      acc[1][0] += a1 * b0; acc[1][1] += a1 * b1; acc[1][2] += a1 * b2; acc[1][3] += a1 * b3;
      acc[2][0] += a2 * b0; acc[2][1] += a2 * b1; acc[2][2] += a2 * b2; acc[2][3] += a2 * b3;
      acc[3][0] += a3 * b0; acc[3][1] += a3 * b1; acc[3][2] += a3 * b2; acc[3][3] += a3 * b3;
    }
    __syncthreads();
  }

  #pragma unroll
  for (int v = 0; v < 4; ++v) {
    int mrow = ca + ty + 16 * v;
    #pragma unroll
    for (int u = 0; u < 4; ++u) {
      int ncol = cb + tx + 16 * u;
      if (mrow < K_ && ncol < K_)
        atomicAdd(&rrg[(size_t)mrow * K_ + ncol], acc[v][u]);
    }
  }
}

// ---------------- symmetrize accumulated upper -> rr (full square, LD) -----
__global__ __launch_bounds__(256) void k_reduce(const double* __restrict__ rrg,
                                                double* __restrict__ rr)
{
  int idx = blockIdx.x * 256 + threadIdx.x;   // packed lower-tri index
  if (idx >= TRI_N) return;
  int i = (int)((sqrtf(8.f * (float)idx + 1.f) - 1.f) * 0.5f);
  while ((i + 1) * (i + 2) / 2 <= idx) ++i;
  while (i * (i + 1) / 2 > idx) --i;
  int j = idx - (i * (i + 1)) / 2;            // j <= i
  double s = rrg[(size_t)j * K_ + i];         // valid entries live at (min,max)
  rr[i * LD + j] = s;
  rr[j * LD + i] = s;
}

// ---------------- LDS-resident small linear algebra ------------------------
__global__ __launch_bounds__(1024) void k_small2(
    const double* __restrict__ rr, const double* __restrict__ m,
    double* __restrict__ invsq, float* __restrict__ sq32,
    float* __restrict__ normv)
{
  extern __shared__ double smem[];
  double* tri = smem;               // 18336
  double* m_s = smem + TRI_N;       // 192
  double* w1  = m_s + 192;          // 192
  double* tmp = w1 + 192;           // 32*33 = 1056
  const int t = threadIdx.x;
  __shared__ double spiv;

  if (t < K_) m_s[t] = m[t];
  for (int i = t >> 5; i < K_; i += 32) {
    int base = (i * (i + 1)) / 2;
    for (int j = t & 31; j <= i; j += 32) {
      double v = rr[i * LD + j];
      tri[base + j] = (i == j) ? v + 1e-6 : v;
    }
  }
  __syncthreads();

  // Cholesky (right-looking, packed triangle in LDS)
  for (int k = 0; k < K_; ++k) {
    if (t == 0) {
      double d = sqrt(tri[(k * (k + 1)) / 2 + k]);
      tri[(k * (k + 1)) / 2 + k] = d; spiv = d;
    }
    __syncthreads();
    double piv = spiv;
    for (int r = k + 1 + t; r < K_; r += 1024)
      tri[(r * (r + 1)) / 2 + k] /= piv;
    __syncthreads();
    {
      int tx = t & 31, ty = t >> 5;
      for (int r = k + 1 + ty; r < K_; r += 32) {
        int rb = (r * (r + 1)) / 2;
        double lrk = tri[rb + k];
        for (int c = k + 1 + tx; c <= r; c += 32)
          tri[rb + c] -= lrk * tri[(c * (c + 1)) / 2 + k];
      }
    }
    __syncthreads();
  }

  // blocked in-place trtri: tri <- X = L^{-1}
  for (int J = 0; J < 6; ++J) {
    int j0 = J * 32;
    int nb = (K_ - j0 < 32) ? (K_ - j0) : 32;
    if (t < nb) {
      int c = t;
      for (int r = c; r < nb; ++r) {
        double s = (r == c) ? 1.0 : 0.0;
        int rb = ((j0 + r) * (j0 + r + 1)) / 2 + j0;
        for (int k = c; k < r; ++k) s -= tri[rb + k] * tmp[k * 33 + c];
        tmp[r * 33 + c] = s / tri[rb + r];
      }
    }
    __syncthreads();
    if (t < nb) {
      int c = t;
      for (int r = c; r < nb; ++r)
        tri[((j0 + r) * (j0 + r + 1)) / 2 + j0 + c] = tmp[r * 33 + c];
    }
    __syncthreads();
  }
  for (int J = 0; J < 5; ++J) {
    int j0 = J * 32;
    for (int I = J + 1; I < 6; ++I) {
      int i0 = I * 32;
      int nbi = (K_ - i0 < 32) ? (K_ - i0) : 32;
      int r = t & 31, c = t >> 5;
      double acc = 0.0;
      if (r < nbi) {
        int ri = i0 + r;
        int rb = (ri * (ri + 1)) / 2;
        for (int k = j0 + c; k < j0 + 32; ++k)
          acc += tri[rb + k] * tri[(k * (k + 1)) / 2 + j0 + c];
        for (int k = j0 + 32; k < i0; ++k)
          acc += tri[rb + k] * tri[(k * (k + 1)) / 2 + j0 + c];
      }
      tmp[r * 33 + c] = acc;
      __syncthreads();
      double out = 0.0;
      if (r < nbi) {
        int ri = i0 + r;
        int rb = (ri * (ri + 1)) / 2;
        for (int k = 0; k <= r; ++k)
          out -= tri[rb + i0 + k] * tmp[k * 33 + c];
        tri[rb + j0 + c] = out;
      }
      __syncthreads();
    }
  }

  if (t < K_) {
    int r = t, rb = (r * (r + 1)) / 2;
    double s = 0.0;
    for (int p = 0; p <= r; ++p) s += tri[rb + p] * m_s[p];
    w1[r] = s;
  }
  __syncthreads();
  if (t < K_) {
    int i = t;
    double s2 = 0.0, s1 = 0.0;
    for (int r = i; r < K_; ++r) {
      double xv = tri[(r * (r + 1)) / 2 + i];
      s2 += xv * xv;
      s1 += xv * w1[r];
    }
    double dii = s2;
    double q = 1.0 / dii;
    double sm_ = s1 / dii;
    double var = (q - sm_ * sm_ / (double)N_) / (double)(N_ - 1);
    double t1 = sqrt(var) + 1e-30;
    double om = t1 * t1;
    invsq[i] = 1.0 / sqrt(om);
    sq32[i] = sqrtf((float)om);
    tmp[i] = rr[i * LD + i] / om;
  }
  __syncthreads();
  if (t == 0) {
    double s = 0.0;
    for (int i = 0; i < K_; ++i) s += tmp[i];
    *normv = (float)s;
  }
}

// ---------------- CholQR helper (operates on shQ K_ x MSUB, shS MSUB x 17) -
__device__ __forceinline__ void cholqr(double* shQ, double* shS, int t)
{
  // S = Q^T Q
  if (t < MSUB * MSUB) {
    int a = t & (MSUB - 1), b = t >> 4;
    double s = 0.0;
    for (int r = 0; r < K_; ++r) s += shQ[r * MSUB + a] * shQ[r * MSUB + b];
    shS[b * 17 + a] = s;
  }
  __syncthreads();
  // Cholesky 16x16 (lower)
  for (int k = 0; k < MSUB; ++k) {
    if (t == 0) shS[k * 17 + k] = sqrt(shS[k * 17 + k]);
    __syncthreads();
    if (t > k && t < MSUB) shS[t * 17 + k] /= shS[k * 17 + k];
    __syncthreads();
    if (t < MSUB * MSUB) {
      int r = t & (MSUB - 1), c = t >> 4;
      if (c > k && r >= c) shS[r * 17 + c] -= shS[r * 17 + k] * shS[c * 17 + k];
    }
    __syncthreads();
  }
  // rows solve: Qnew L^T = Qold
  if (t < K_) {
    double q[MSUB];
    #pragma unroll
    for (int c = 0; c < MSUB; ++c) {
      double v = shQ[t * MSUB + c];
      for (int p = 0; p < c; ++p) v -= q[p] * shS[c * 17 + p];
      q[c] = v / shS[c * 17 + c];
    }
    #pragma unroll
    for (int c = 0; c < MSUB; ++c) shQ[t * MSUB + c] = q[c];
  }
  __syncthreads();
}

// ---------------- one-block subspace iteration, top-16 eigenpairs ----------
// G = D rr D staged as packed f32 lower triangle in LDS; all else f64 LDS.
__global__ __launch_bounds__(512) void k_sub(
    const double* __restrict__ rr, const double* __restrict__ invsq,
    float* __restrict__ W1, float* __restrict__ W2)
{
  extern __shared__ double dsm[];
  double* shQ  = dsm;                 // 3056
  double* shZ  = shQ + 3056;          // 3056
  double* shS  = shZ + 3056;          // 272 (16*17)
  double* Ws   = shS + 272;           // 272
  double* inv_s= Ws + 272;            // 192
  double* ev   = inv_s + 192;         // 16
  double* cs_  = ev + 16;             // 8
  double* sn_  = cs_ + 8;             // 8
  int* ipp  = (int*)(sn_ + 8);        // 8
  int* iqq  = ipp + 8;                // 8
  int* perm = iqq + 8;                // 16
  float* tri = (float*)(perm + 16);   // 18336
  const int t = threadIdx.x;

  if (t < K_) inv_s[t] = invsq[t];
  __syncthreads();
  // stage G lower triangle (f32): G_ij = rr_ij * invsq_i * invsq_j
  for (int i = t >> 4; i < K_; i += 32) {
    int base = (i * (i + 1)) / 2;
    double di = inv_s[i];
    for (int j = t & 15; j <= i; j += 16)
      tri[base + j] = (float)(rr[i * LD + j] * di * inv_s[j]);
  }
  __syncthreads();

  // init Q = G[:, 0:16]
  for (int idx = t; idx < K_ * MSUB; idx += 512) {
    int i = idx >> 4, c = idx & 15;
    float g = (i >= c) ? tri[(i * (i + 1)) / 2 + c] : tri[(c * (c + 1)) / 2 + i];
    shQ[idx] = (double)g;
  }
  __syncthreads();

  cholqr(shQ, shS, t);
  for (int it = 0; it < 4; ++it) {
    // copy Q -> Z
    for (int idx = t; idx < K_ * MSUB; idx += 512) shZ[idx] = shQ[idx];
    __syncthreads();
    // Q = G * Z   (triangular-packed G)
    for (int idx = t; idx < K_ * MSUB; idx += 512) {
      int i = idx >> 4, c = idx & 15;
      double s = 0.0;
      int rb = (i * (i + 1)) >> 1;
      for (int k = 0; k <= i; ++k) s += (double)tri[rb + k] * shZ[k * MSUB + c];
      int kk = ((i + 1) * (i + 2)) >> 1;
      for (int k = i + 1; k < K_; ++k) { s += (double)tri[kk + i] * shZ[k * MSUB + c]; kk += k + 1; }
      shQ[idx] = s;
    }
    __syncthreads();
    if (it < 3) cholqr(shQ, shS, t);
  }
  // here: shZ = Q_orth, shQ = G*Q_orth.  T = Z^T Q  -> shS
  if (t < MSUB * MSUB) {
    int a = t & 15, b = t >> 4;
    double s = 0.0;
    for (int r = 0; r < K_; ++r) s += shZ[r * MSUB + b] * shQ[r * MSUB + a];
    shS[b * 17 + a] = s;
  }
  // init Ws = I
  if (t < MSUB * 17) Ws[t] = 0.0;
  __syncthreads();
  if (t < MSUB) Ws[t * 17 + t] = 1.0;
  __syncthreads();
  // Jacobi eigensolve of 16x16 T
  for (int sweep = 0; sweep < 6; ++sweep) {
    for (int round = 0; round < 15; ++round) {
      if (t < 8) {
        int ia = (t == 0) ? 0 : (1 + ((t - 1 + round) % 15));
        int ib = 1 + ((14 - t + round) % 15);
        int p = ia < ib ? ia : ib;
        int q = ia < ib ? ib : ia;
        double app = shS[p * 17 + p], aqq = shS[q * 17 + q], apq = shS[p * 17 + q];
        double c = 1.0, s = 0.0;
        if (fabs(apq) > 1e-30 * (fabs(app) + fabs(aqq)) && apq != 0.0) {
          double tau = (aqq - app) / (2.0 * apq);
          double tt = (tau >= 0.0 ? 1.0 : -1.0) / (fabs(tau) + sqrt(1.0 + tau * tau));
          c = 1.0 / sqrt(1.0 + tt * tt); s = tt * c;
        }
        cs_[t] = c; sn_[t] = s; ipp[t] = p; iqq[t] = q;
      }
      __syncthreads();
      if (t < 128) {   // column rotations of T and Ws
        int i = t & 15, mI = t >> 4;
        int p = ipp[mI], q = iqq[mI];
        double c = cs_[mI], s = sn_[mI];
        double u = shS[i * 17 + p], v = shS[i * 17 + q];
        shS[i * 17 + p] = c * u - s * v; shS[i * 17 + q] = s * u + c * v;
        double wu = Ws[i * 17 + p], wv = Ws[i * 17 + q];
        Ws[i * 17 + p] = c * wu - s * wv; Ws[i * 17 + q] = s * wu + c * wv;
      }
      __syncthreads();
      if (t < 128) {   // row rotations of T
        int j = t & 15, mI = t >> 4;
        int p = ipp[mI], q = iqq[mI];
        double c = cs_[mI], s = sn_[mI];
        double u = shS[p * 17 + j], v = shS[q * 17 + j];
        shS[p * 17 + j] = c * u - s * v; shS[q * 17 + j] = s * u + c * v;
      }
      __syncthreads();
    }
  }
  if (t == 0) {
    for (int i = 0; i < MSUB; ++i) { ev[i] = shS[i * 17 + i]; perm[i] = i; }
    for (int i = 0; i < MSUB; ++i) {
      int best = i;
      for (int j = i + 1; j < MSUB; ++j)
        if (ev[perm[j]] > ev[perm[best]]) best = j;
      int tp = perm[i]; perm[i] = perm[best]; perm[best] = tp;
    }
  }
  __syncthreads();
  // E = Q_orth * Ws (sorted); W1[i][c] = invsq_i * E ; W2[c][i] = E * sqrt(om_i)
  for (int idx = t; idx < K_ * MSUB; idx += 512) {
    int i = idx >> 4, c = idx & 15;
    int pc_ = perm[c];
    double e = 0.0;
    #pragma unroll
    for (int p = 0; p < MSUB; ++p) e += shZ[i * MSUB + p] * Ws[p * 17 + pc_];
    W1[i * MSUB + c] = (float)(inv_s[i] * e);
    W2[c * K_ + i]   = (float)(e / inv_s[i]);
  }
}

// ---------------- pc = x * W1 (f32), channel-major output ------------------
__global__ __launch_bounds__(256) void k_pc(const float* __restrict__ x,
                                            const float* __restrict__ W1,
                                            float* __restrict__ pc)
{
  __shared__ float xs[32][192];
  __shared__ float w1s[K_ * MSUB];
  int t = threadIdx.x;
  long n0 = (long)blockIdx.x * 32;
  for (int idx = t; idx < K_ * MSUB; idx += 256) w1s[idx] = W1[idx];
  for (int idx = t; idx < 32 * K_; idx += 256) {
    int row = idx / K_, col = idx - row * K_;
    xs[row][col] = x[(n0 + row) * K_ + col];
  }
  __syncthreads();
  int c = t & 15, nl = t >> 4;         // nl in [0,16)
  float a0 = 0.f, a1 = 0.f;
  for (int k = 0; k < K_; ++k) {
    float w = w1s[k * MSUB + c];
    a0 += xs[nl][k] * w;
    a1 += xs[nl + 16][k] * w;
  }
  __syncthreads();
  float* ts = &xs[0][0];               // reuse as 16x33 transpose buffer
  ts[c * 33 + nl]      = a0;
  ts[c * 33 + nl + 16] = a1;
  __syncthreads();
  for (int idx = t; idx < MSUB * 32; idx += 256) {
    int cc = idx >> 5, nn = idx & 31;
    pc[(size_t)cc * N_ + n0 + nn] = ts[cc * 33 + nn];
  }
}

// ---------------- DWT: vertical analysis pass ------------------------------
__global__ __launch_bounds__(256) void k_dwtv(const float* __restrict__ in,
                                              float* __restrict__ outv, int s)
{
  long gid = (long)blockIdx.x * 256 + threadIdx.x;
  int h = s >> 1;
  long per = (long)h * s;
  if (gid >= MSUB * per) return;
  int ch = (int)(gid / per);
  long rem = gid - (long)ch * per;
  int r = (int)(rem / s);
  int col = (int)(rem - (long)r * s);
  const float* cin = in + (long)ch * s * s;
  float la = 0.f, ld_ = 0.f;
  int base = 2 * r;
  #pragma unroll
  for (int l = 0; l < 10; ++l) {
    int rr_ = base + l; if (rr_ >= s) rr_ -= s;
    float v = cin[(long)rr_ * s + col];
    la += c_lo[l] * v; ld_ += c_hi[l] * v;
  }
  float* cout = outv + (long)ch * s * s;
  cout[(long)r * s + col] = la;
  cout[(long)(h + r) * s + col] = ld_;
}

// ---------------- DWT: horizontal analysis pass ----------------------------
__global__ __launch_bounds__(256) void k_dwth(const float* __restrict__ inv,
                                              float* __restrict__ llout,
                                              float* __restrict__ coef,
                                              int s, long offL, int last)
{
  long gid = (long)blockIdx.x * 256 + threadIdx.x;
  int h = s >> 1;
  long per = (long)s * h;
  if (gid >= MSUB * per) return;
  int ch = (int)(gid / per);
  long rem = gid - (long)ch * per;
  int r = (int)(rem / h);
  int mcol = (int)(rem - (long)r * h);
  const float* row = inv + (long)ch * s * s + (long)r * s;
  float lo = 0.f, hi = 0.f;
  int base = 2 * mcol;
  #pragma unroll
  for (int l = 0; l < 10; ++l) {
    int cc = base + l; if (cc >= s) cc -= s;
    float v = row[cc];
    lo += c_lo[l] * v; hi += c_hi[l] * v;
  }
  float* cslab = coef + (size_t)ch * N_ + offL;
  if (r < h) {
    llout[(size_t)ch * h * h + (long)r * h + mcol] = lo;
    if (last) coef[(size_t)ch * N_ + 147312 + (long)r * h + mcol] = lo;
    cslab[(long)r * h + mcol] = hi;
  } else {
    int rd = r - h;
    cslab[(long)h * h + (long)rd * h + mcol] = lo;
    cslab[(long)2 * h * h + (long)rd * h + mcol] = hi;
  }
}

// ---------------- SURE statistics per channel ------------------------------
__global__ __launch_bounds__(256) void k_stats(const float* __restrict__ coef,
                                               float* __restrict__ stats)
{
  int ch = blockIdx.x;
  int t = threadIdx.x;
  float T2[NT];
  {
    double stop = sqrt(log(147456.0));
    double step = stop / 14.0;
    for (int i = 0; i < NT; ++i) {
      double td = (i == 14) ? stop : (double)i * step;
      float tf = (float)td;
      T2[i] = tf * tf;
    }
  }
  float cn = 0.f, sm[NT], ct[NT];
  #pragma unroll
  for (int i = 0; i < NT; ++i) { sm[i] = 0.f; ct[i] = 0.f; }
  const float* base = coef + (size_t)ch * N_;
  for (int idx = t; idx < N_; idx += 256) {
    float v = base[idx];
    float v2 = v * v;
    cn += v2;
    #pragma unroll
    for (int i = 0; i < NT; ++i) {
      sm[i] += fminf(v2, T2[i]);
      ct[i] += (v2 > T2[i]) ? 1.0f : 0.0f;
    }
  }
  __shared__ float red[256];
  for (int a = 0; a < 31; ++a) {
    float val = (a == 0) ? cn : ((a < 16) ? sm[a - 1] : ct[a - 16]);
    red[t] = val;
    __syncthreads();
    for (int off = 128; off > 0; off >>= 1) {
      if (t < off) red[t] += red[t + off];
      __syncthreads();
    }
    if (t == 0) stats[ch * 31 + a] = red[0];
    __syncthreads();
  }
}

// ---------------- SURE scan + rank -----------------------------------------
__global__ void k_rank(const float* __restrict__ stats,
                       const float* __restrict__ normv, int* __restrict__ rankp)
{
  if (threadIdx.x != 0 || blockIdx.x != 0) return;
  float c_const = *normv - 28164096.0f;
  float acc[NT];
  for (int i = 0; i < NT; ++i) acc[i] = 0.f;
  float minsure[MSUB];
  for (int r = 0; r < MSUB; ++r) {
    float cn = stats[r * 31 + 0];
    float mn = 3.4e38f;
    for (int i = 0; i < NT; ++i) {
      float sure = stats[r * 31 + 1 + i] + 2.0f * stats[r * 31 + 16 + i] - cn;
      float s_r = acc[i] + sure + c_const;
      acc[i] = acc[i] + s_r;
      if (s_r < mn) mn = s_r;
    }
    minsure[r] = mn;
  }
  int rank = -1;
  for (int r = 2; r < MSUB; ++r) {
    if (minsure[r] > minsure[r - 1]) { rank = r; break; }
  }
  if (rank < 0) rank = MSUB - 1;
  *rankp = rank;
}

// ---------------- output: out = sqrt(omega) .* (pc[:, :rank] @ vh) ---------
__global__ __launch_bounds__(256) void k_out(const float* __restrict__ pc,
                                             const float* __restrict__ W2,
                                             const int* __restrict__ rankp,
                                             float* __restrict__ out)
{
  long gid = (long)blockIdx.x * 256 + threadIdx.x;
  int n = (int)(gid / K_);
  int j = (int)(gid - (long)n * K_);
  int rank = *rankp;
  float acc = 0.f;
  for (int c = 0; c < rank; ++c)
    acc += pc[(size_t)c * N_ + n] * W2[c * K_ + j];
  out[gid] = acc;
}

extern "C" void kernel_launch(void* const* d_in, const int* in_sizes, int n_in,
                              void* d_out, int out_size, void* d_ws, size_t ws_size,
                              hipStream_t stream)
{
  if (n_in < 1 || in_sizes[0] != N_ * K_) return;
  const float* x = (const float*)d_in[0];
  float* out = (float*)d_out;
  (void)out_size;

  char* w = (char*)d_ws;
  size_t off = 0;
  auto alloc = [&](size_t bytes) -> char* {
    char* p = w + off;
    off = (off + bytes + 255) & ~(size_t)255;
    return p;
  };
  double* m_    = (double*)alloc(K_ * 8);
  double* rrp   = (double*)alloc((size_t)K_ * K_ * 8);   // atomically-accumulated Gram
  double* rr    = (double*)alloc((size_t)K_ * LD * 8);
  double* invsq = (double*)alloc(K_ * 8);
  float*  sq32  = (float*)alloc(K_ * 4);
  float*  normv = (float*)alloc(256);
  float*  W1    = (float*)alloc((size_t)K_ * MSUB * 4);
  float*  W2    = (float*)alloc((size_t)MSUB * K_ * 4);
  float*  pc    = (float*)alloc((size_t)MSUB * N_ * 4);
  float*  tmpv  = (float*)alloc((size_t)MSUB * N_ * 4);
  float*  coef  = (float*)alloc((size_t)MSUB * N_ * 4);
  float*  curA  = (float*)alloc((size_t)MSUB * 192 * 192 * 4);
  float*  curB  = (float*)alloc((size_t)MSUB * 96 * 96 * 4);
  float*  stats = (float*)alloc((size_t)MSUB * 31 * 4);
  int*    rankp = (int*)alloc(256);
  if (off > ws_size) return;

  hipMemsetAsync(m_, 0, K_ * sizeof(double), stream);
  hipMemsetAsync(rrp, 0, (size_t)K_ * K_ * sizeof(double), stream);

  hipFuncSetAttribute(reinterpret_cast<const void*>(k_small2),
                      hipFuncAttributeMaxDynamicSharedMemorySize, SMEM_SZ);
  hipFuncSetAttribute(reinterpret_cast<const void*>(k_sub),
                      hipFuncAttributeMaxDynamicSharedMemorySize, SMEM2_SZ);

  k_colsum<<<N_ / 512, 256, 0, stream>>>(x, m_);
  k_rr<<<NPAIR * NSPLIT, 256, 0, stream>>>(x, rrp);
  k_reduce<<<(TRI_N + 255) / 256, 256, 0, stream>>>(rrp, rr);
  k_small2<<<1, 1024, SMEM_SZ, stream>>>(rr, m_, invsq, sq32, normv);
  k_sub<<<1, 512, SMEM2_SZ, stream>>>(rr, invsq, W1, W2);
  k_pc<<<N_ / 32, 256, 0, stream>>>(x, W1, pc);

  int   sizes[5] = {384, 192, 96, 48, 24};
  long  offs[5]  = {0, 110592, 138240, 145152, 146880};
  float* lls[5]  = {curA, curB, curA, curB, curA};
  const float* curin = pc;
  for (int lev = 0; lev < 5; ++lev) {
    int s = sizes[lev], h = s >> 1;
    long nth = (long)MSUB * h * s;
    k_dwtv<<<(int)((nth + 255) / 256), 256, 0, stream>>>(curin, tmpv, s);
    k_dwth<<<(int)((nth + 255) / 256), 256, 0, stream>>>(tmpv, lls[lev], coef,
                                                         s, offs[lev],
                                                         lev == 4 ? 1 : 0);
    curin = lls[lev];
  }

  k_stats<<<MSUB, 256, 0, stream>>>(coef, stats);
  k_rank<<<1, 64, 0, stream>>>(stats, normv, rankp);
  k_out<<<(N_ * K_) / 256, 256, 0, stream>>>(pc, W2, rankp, out);
}

// Round 3
// 1663.187 us; speedup vs baseline: 1.1578x; 1.0130x over previous
//
#include <hip/hip_runtime.h>
#include <math.h>

#define K_     191
#define LD     192
#define N_     147456
#define MSUB   16
#define NT     15
#define TRI_N  18336   // 191*192/2
#define SMEM_SZ ((TRI_N + 192 + 192 + 1056) * 8)
// k_sub dynamic LDS: 6880 doubles + 32 ints + 18336 floats
#define SMEM2_SZ (6880 * 8 + 32 * 4 + TRI_N * 4)

// k_rr geometry: 64-wide col blocks, 6 pairs, 128 K-splits
#define NPAIR  6
#define NSPLIT 128
#define CHUNK  (N_ / NSPLIT)   // 1152
#define RSTEP  32

// db5 decomposition filters (pywt convention), f32 as in reference
__constant__ float c_lo[10] = {
  0.003335725285001549f, -0.012580751999015526f, -0.006241490213011705f,
  0.07757149384006515f,  -0.03224486958502952f, -0.24229488706619015f,
  0.13842814590110342f,   0.7243085284385744f,   0.6038292697974729f,
  0.160102397974125f };
__constant__ float c_hi[10] = {
  0.160102397974125f,    -0.6038292697974729f,   0.7243085284385744f,
 -0.13842814590110342f,  -0.24229488706619015f,  0.03224486958502952f,
  0.07757149384006515f,   0.006241490213011705f,-0.012580751999015526f,
 -0.003335725285001549f };

// ---------------- column sums of x (f64), for the regression mean ----------
__global__ __launch_bounds__(256) void k_colsum(const float* __restrict__ x,
                                                double* __restrict__ m)
{
  int t = threadIdx.x;
  long base = (long)blockIdx.x * 512;
  if (t < K_) {
    double s = 0.0;
    const float* p = x + base * K_ + t;
    for (int r = 0; r < 512; ++r) s += (double)p[(long)r * K_];
    atomicAdd(&m[t], s);
  }
}

// ---------------- rr = x^T x, register-tiled VALU f64, split-K atomics -----
__global__ __launch_bounds__(256, 3) void k_rr(const float* __restrict__ x,
                                               double* __restrict__ rrg)
{
  __shared__ double Asd[RSTEP][64];
  __shared__ double Bsd[RSTEP][64];

  const int bid   = blockIdx.x;
  const int split = bid & (NSPLIT - 1);
  const int pair  = bid >> 7;
  const int BI[6] = {0, 0, 0, 1, 1, 2};
  const int BJ[6] = {0, 1, 2, 1, 2, 2};
  const int bi = BI[pair], bj = BJ[pair];
  const int ca = bi * 64, cb = bj * 64;

  const int t  = threadIdx.x;
  const int tx = t & 15, ty = t >> 4;
  const long n0 = (long)split * CHUNK;

  double acc[4][4];
  #pragma unroll
  for (int v = 0; v < 4; ++v)
    #pragma unroll
    for (int u = 0; u < 4; ++u) acc[v][u] = 0.0;

  for (int r0 = 0; r0 < CHUNK; r0 += RSTEP) {
    for (int s = t; s < RSTEP * 16; s += 256) {
      int row = s >> 4, g = s & 15;
      long gr = (n0 + r0 + row) * (long)K_;
      int c4a = ca + g * 4, c4b = cb + g * 4;
      #pragma unroll
      for (int e = 0; e < 4; ++e) {
        Asd[row][g * 4 + e] = (c4a + e < K_) ? (double)x[gr + c4a + e] : 0.0;
        Bsd[row][g * 4 + e] = (c4b + e < K_) ? (double)x[gr + c4b + e] : 0.0;
      }
    }
    __syncthreads();
    #pragma unroll 4
    for (int k = 0; k < RSTEP; ++k) {
      double a0 = Asd[k][ty],      a1 = Asd[k][ty + 16];
      double a2 = Asd[k][ty + 32], a3 = Asd[k][ty + 48];
      double b0 = Bsd[k][tx],      b1 = Bsd[k][tx + 16];
      double b2 = Bsd[k][tx + 32], b3 = Bsd[k][tx + 48];
      acc[0][0] += a0 * b0; acc[0][1] += a0 * b1; acc[0][2] += a0 * b2; acc[0][3] += a0 * b3;
      acc[1][0] += a1 * b0; acc[1][1] += a1 * b1; acc[1][2] += a1 * b2; acc[1][3] += a1 * b3;
      acc[2][0] += a2 * b0; acc[2][1] += a2 * b1; acc[2][2] += a2 * b2; acc[2][3] += a2 * b3;
      acc[3][0] += a3 * b0; acc[3][1] += a3 * b1; acc[3][2] += a3 * b2; acc[3][3] += a3 * b3;
    }
    __syncthreads();
  }

  #pragma unroll
  for (int v = 0; v < 4; ++v) {
    int mrow = ca + ty + 16 * v;
    #pragma unroll
    for (int u = 0; u < 4; ++u) {
      int ncol = cb + tx + 16 * u;
      if (mrow < K_ && ncol < K_)
        atomicAdd(&rrg[(size_t)mrow * K_ + ncol], acc[v][u]);
    }
  }
}

// ---------------- symmetrize accumulated upper -> rr (full square, LD) -----
__global__ __launch_bounds__(256) void k_reduce(const double* __restrict__ rrg,
                                                double* __restrict__ rr)
{
  int idx = blockIdx.x * 256 + threadIdx.x;   // packed lower-tri index
  if (idx >= TRI_N) return;
  int i = (int)((sqrtf(8.f * (float)idx + 1.f) - 1.f) * 0.5f);
  while ((i + 1) * (i + 2) / 2 <= idx) ++i;
  while (i * (i + 1) / 2 > idx) --i;
  int j = idx - (i * (i + 1)) / 2;            // j <= i
  double s = rrg[(size_t)j * K_ + i];         // valid entries live at (min,max)
  rr[i * LD + j] = s;
  rr[j * LD + i] = s;
}

// ---------------- LDS-resident small linear algebra ------------------------
// Blocked Cholesky (BS=32): wave-register diag factor + parallel panel solve
// + 4x4-register-tiled trailing update.  trtri + finals unchanged.
__global__ __launch_bounds__(1024) void k_small2(
    const double* __restrict__ rr, const double* __restrict__ m,
    double* __restrict__ invsq, float* __restrict__ sq32,
    float* __restrict__ normv)
{
  extern __shared__ double smem[];
  double* tri = smem;               // 18336
  double* m_s = smem + TRI_N;       // 192
  double* w1  = m_s + 192;          // 192
  double* tmp = w1 + 192;           // 32*33 = 1056 (also inv-diag scratch)
  const int t = threadIdx.x;

  if (t < K_) m_s[t] = m[t];
  for (int i = t >> 5; i < K_; i += 32) {
    int base = (i * (i + 1)) / 2;
    for (int j = t & 31; j <= i; j += 32) {
      double v = rr[i * LD + j];
      tri[base + j] = (i == j) ? v + 1e-6 : v;
    }
  }
  __syncthreads();

  // ---- blocked Cholesky, 6 panels of 32 columns ----
  for (int J = 0; J < 6; ++J) {
    const int j0 = J * 32;
    const int nb = (K_ - j0 < 32) ? (K_ - j0) : 32;   // 32,32,32,32,32,31

    // Phase A: wave 0 factors the diag block in registers (lane = row).
    // All column indices are compile-time -> no scratch; __shfl with
    // constant src lane -> v_readlane broadcast; zero barriers inside.
    if (t < 64) {
      const int rl = t & 31;
      double a[32];
      #pragma unroll
      for (int c = 0; c < 32; ++c) {
        int i = j0 + rl;
        a[c] = (c <= rl && rl < nb) ? tri[(i * (i + 1)) / 2 + j0 + c] : 0.0;
      }
      #pragma unroll
      for (int k = 0; k < 32; ++k) {
        double akk = __shfl(a[k], k);
        double piv = sqrt(akk);
        double inv = 1.0 / piv;
        if (t == k) tmp[k] = inv;          // save reciprocal diag for panel
        a[k] = (rl == k) ? piv : a[k] * inv;
        #pragma unroll
        for (int c = k + 1; c < 32; ++c) {
          double lck = __shfl(a[k], c);    // L[j0+c][j0+k]
          if (c <= rl) a[c] -= a[k] * lck;
        }
      }
      if (t < 32 && rl < nb) {
        int i = j0 + rl;
        int rb = (i * (i + 1)) / 2 + j0;
        #pragma unroll
        for (int c = 0; c < 32; ++c)
          if (c <= rl) tri[rb + c] = a[c];
      }
    }
    __syncthreads();

    // Phase B: panel solve, one row per thread (only when rows exist below;
    // nb==32 whenever there are rows below).
    {
      int p = j0 + 32 + t;
      if (nb == 32 && p < K_) {
        int pb = (p * (p + 1)) / 2 + j0;
        double v[32];
        #pragma unroll
        for (int c = 0; c < 32; ++c) v[c] = tri[pb + c];
        #pragma unroll
        for (int c = 0; c < 32; ++c) {
          double s = v[c];
          #pragma unroll
          for (int q = 0; q < c; ++q) {
            int cc = j0 + c;
            s -= v[q] * tri[(cc * (cc + 1)) / 2 + j0 + q];
          }
          v[c] = s * tmp[c];
        }
        #pragma unroll
        for (int c = 0; c < 32; ++c) tri[pb + c] = v[c];
      }
    }
    __syncthreads();

    // Phase C: trailing update A -= L_panel L_panel^T, 4x4 register tiles.
    {
      int s0 = j0 + 32;
      int n = K_ - s0;
      if (n > 0) {
        int R4 = (n + 3) >> 2;
        int T4 = R4 * (R4 + 1) / 2;
        for (int tile = t; tile < T4; tile += 1024) {
          int ti = (int)((sqrtf(8.f * (float)tile + 1.f) - 1.f) * 0.5f);
          while ((ti + 1) * (ti + 2) / 2 <= tile) ++ti;
          while (ti * (ti + 1) / 2 > tile) --ti;
          int tj = tile - ti * (ti + 1) / 2;
          int r0 = s0 + ti * 4, c0 = s0 + tj * 4;
          int rb[4], cb[4];
          #pragma unroll
          for (int u = 0; u < 4; ++u) {
            int r = (r0 + u < K_) ? r0 + u : K_ - 1;
            rb[u] = (r * (r + 1)) / 2;
            int c = (c0 + u < K_) ? c0 + u : K_ - 1;
            cb[u] = (c * (c + 1)) / 2;
          }
          double acc[4][4];
          #pragma unroll
          for (int u = 0; u < 4; ++u)
            #pragma unroll
            for (int v2 = 0; v2 < 4; ++v2) acc[u][v2] = 0.0;
          #pragma unroll 4
          for (int p = 0; p < 32; ++p) {
            double lr[4], lc[4];
            #pragma unroll
            for (int u = 0; u < 4; ++u) {
              lr[u] = tri[rb[u] + j0 + p];
              lc[u] = tri[cb[u] + j0 + p];
            }
            #pragma unroll
            for (int u = 0; u < 4; ++u)
              #pragma unroll
              for (int v2 = 0; v2 < 4; ++v2) acc[u][v2] += lr[u] * lc[v2];
          }
          #pragma unroll
          for (int u = 0; u < 4; ++u) {
            int r = r0 + u;
            if (r < K_) {
              #pragma unroll
              for (int v2 = 0; v2 < 4; ++v2) {
                int c = c0 + v2;
                if (c <= r) tri[rb[u] + c] -= acc[u][v2];
              }
            }
          }
        }
      }
    }
    __syncthreads();
  }

  // blocked in-place trtri: tri <- X = L^{-1}
  for (int J = 0; J < 6; ++J) {
    int j0 = J * 32;
    int nb = (K_ - j0 < 32) ? (K_ - j0) : 32;
    if (t < nb) {
      int c = t;
      for (int r = c; r < nb; ++r) {
        double s = (r == c) ? 1.0 : 0.0;
        int rb = ((j0 + r) * (j0 + r + 1)) / 2 + j0;
        for (int k = c; k < r; ++k) s -= tri[rb + k] * tmp[k * 33 + c];
        tmp[r * 33 + c] = s / tri[rb + r];
      }
    }
    __syncthreads();
    if (t < nb) {
      int c = t;
      for (int r = c; r < nb; ++r)
        tri[((j0 + r) * (j0 + r + 1)) / 2 + j0 + c] = tmp[r * 33 + c];
    }
    __syncthreads();
  }
  for (int J = 0; J < 5; ++J) {
    int j0 = J * 32;
    for (int I = J + 1; I < 6; ++I) {
      int i0 = I * 32;
      int nbi = (K_ - i0 < 32) ? (K_ - i0) : 32;
      int r = t & 31, c = t >> 5;
      double acc = 0.0;
      if (r < nbi) {
        int ri = i0 + r;
        int rb = (ri * (ri + 1)) / 2;
        for (int k = j0 + c; k < j0 + 32; ++k)
          acc += tri[rb + k] * tri[(k * (k + 1)) / 2 + j0 + c];
        for (int k = j0 + 32; k < i0; ++k)
          acc += tri[rb + k] * tri[(k * (k + 1)) / 2 + j0 + c];
      }
      tmp[r * 33 + c] = acc;
      __syncthreads();
      double out = 0.0;
      if (r < nbi) {
        int ri = i0 + r;
        int rb = (ri * (ri + 1)) / 2;
        for (int k = 0; k <= r; ++k)
          out -= tri[rb + i0 + k] * tmp[k * 33 + c];
        tri[rb + j0 + c] = out;
      }
      __syncthreads();
    }
  }

  if (t < K_) {
    int r = t, rb = (r * (r + 1)) / 2;
    double s = 0.0;
    for (int p = 0; p <= r; ++p) s += tri[rb + p] * m_s[p];
    w1[r] = s;
  }
  __syncthreads();
  if (t < K_) {
    int i = t;
    double s2 = 0.0, s1 = 0.0;
    for (int r = i; r < K_; ++r) {
      double xv = tri[(r * (r + 1)) / 2 + i];
      s2 += xv * xv;
      s1 += xv * w1[r];
    }
    double dii = s2;
    double q = 1.0 / dii;
    double sm_ = s1 / dii;
    double var = (q - sm_ * sm_ / (double)N_) / (double)(N_ - 1);
    double t1 = sqrt(var) + 1e-30;
    double om = t1 * t1;
    invsq[i] = 1.0 / sqrt(om);
    sq32[i] = sqrtf((float)om);
    tmp[i] = rr[i * LD + i] / om;
  }
  __syncthreads();
  if (t == 0) {
    double s = 0.0;
    for (int i = 0; i < K_; ++i) s += tmp[i];
    *normv = (float)s;
  }
}

// ---------------- CholQR helper (operates on shQ K_ x MSUB, shS MSUB x 17) -
__device__ __forceinline__ void cholqr(double* shQ, double* shS, int t)
{
  // S = Q^T Q
  if (t < MSUB * MSUB) {
    int a = t & (MSUB - 1), b = t >> 4;
    double s = 0.0;
    for (int r = 0; r < K_; ++r) s += shQ[r * MSUB + a] * shQ[r * MSUB + b];
    shS[b * 17 + a] = s;
  }
  __syncthreads();
  // Cholesky 16x16 (lower)
  for (int k = 0; k < MSUB; ++k) {
    if (t == 0) shS[k * 17 + k] = sqrt(shS[k * 17 + k]);
    __syncthreads();
    if (t > k && t < MSUB) shS[t * 17 + k] /= shS[k * 17 + k];
    __syncthreads();
    if (t < MSUB * MSUB) {
      int r = t & (MSUB - 1), c = t >> 4;
      if (c > k && r >= c) shS[r * 17 + c] -= shS[r * 17 + k] * shS[c * 17 + k];
    }
    __syncthreads();
  }
  // rows solve: Qnew L^T = Qold
  if (t < K_) {
    double q[MSUB];
    #pragma unroll
    for (int c = 0; c < MSUB; ++c) {
      double v = shQ[t * MSUB + c];
      for (int p = 0; p < c; ++p) v -= q[p] * shS[c * 17 + p];
      q[c] = v / shS[c * 17 + c];
    }
    #pragma unroll
    for (int c = 0; c < MSUB; ++c) shQ[t * MSUB + c] = q[c];
  }
  __syncthreads();
}

// ---------------- one-block subspace iteration, top-16 eigenpairs ----------
__global__ __launch_bounds__(512) void k_sub(
    const double* __restrict__ rr, const double* __restrict__ invsq,
    float* __restrict__ W1, float* __restrict__ W2)
{
  extern __shared__ double dsm[];
  double* shQ  = dsm;                 // 3056
  double* shZ  = shQ + 3056;          // 3056
  double* shS  = shZ + 3056;          // 272 (16*17)
  double* Ws   = shS + 272;           // 272
  double* inv_s= Ws + 272;            // 192
  double* ev   = inv_s + 192;         // 16
  double* cs_  = ev + 16;             // 8
  double* sn_  = cs_ + 8;             // 8
  int* ipp  = (int*)(sn_ + 8);        // 8
  int* iqq  = ipp + 8;                // 8
  int* perm = iqq + 8;                // 16
  float* tri = (float*)(perm + 16);   // 18336
  const int t = threadIdx.x;

  if (t < K_) inv_s[t] = invsq[t];
  __syncthreads();
  // stage G lower triangle (f32): G_ij = rr_ij * invsq_i * invsq_j
  for (int i = t >> 4; i < K_; i += 32) {
    int base = (i * (i + 1)) / 2;
    double di = inv_s[i];
    for (int j = t & 15; j <= i; j += 16)
      tri[base + j] = (float)(rr[i * LD + j] * di * inv_s[j]);
  }
  __syncthreads();

  // init Q = G[:, 0:16]
  for (int idx = t; idx < K_ * MSUB; idx += 512) {
    int i = idx >> 4, c = idx & 15;
    float g = (i >= c) ? tri[(i * (i + 1)) / 2 + c] : tri[(c * (c + 1)) / 2 + i];
    shQ[idx] = (double)g;
  }
  __syncthreads();

  cholqr(shQ, shS, t);
  for (int it = 0; it < 4; ++it) {
    // copy Q -> Z
    for (int idx = t; idx < K_ * MSUB; idx += 512) shZ[idx] = shQ[idx];
    __syncthreads();
    // Q = G * Z   (triangular-packed G)
    for (int idx = t; idx < K_ * MSUB; idx += 512) {
      int i = idx >> 4, c = idx & 15;
      double s = 0.0;
      int rb = (i * (i + 1)) >> 1;
      for (int k = 0; k <= i; ++k) s += (double)tri[rb + k] * shZ[k * MSUB + c];
      int kk = ((i + 1) * (i + 2)) >> 1;
      for (int k = i + 1; k < K_; ++k) { s += (double)tri[kk + i] * shZ[k * MSUB + c]; kk += k + 1; }
      shQ[idx] = s;
    }
    __syncthreads();
    if (it < 3) cholqr(shQ, shS, t);
  }
  // here: shZ = Q_orth, shQ = G*Q_orth.  T = Z^T Q  -> shS
  if (t < MSUB * MSUB) {
    int a = t & 15, b = t >> 4;
    double s = 0.0;
    for (int r = 0; r < K_; ++r) s += shZ[r * MSUB + b] * shQ[r * MSUB + a];
    shS[b * 17 + a] = s;
  }
  // init Ws = I
  if (t < MSUB * 17) Ws[t] = 0.0;
  __syncthreads();
  if (t < MSUB) Ws[t * 17 + t] = 1.0;
  __syncthreads();
  // Jacobi eigensolve of 16x16 T
  for (int sweep = 0; sweep < 6; ++sweep) {
    for (int round = 0; round < 15; ++round) {
      if (t < 8) {
        int ia = (t == 0) ? 0 : (1 + ((t - 1 + round) % 15));
        int ib = 1 + ((14 - t + round) % 15);
        int p = ia < ib ? ia : ib;
        int q = ia < ib ? ib : ia;
        double app = shS[p * 17 + p], aqq = shS[q * 17 + q], apq = shS[p * 17 + q];
        double c = 1.0, s = 0.0;
        if (fabs(apq) > 1e-30 * (fabs(app) + fabs(aqq)) && apq != 0.0) {
          double tau = (aqq - app) / (2.0 * apq);
          double tt = (tau >= 0.0 ? 1.0 : -1.0) / (fabs(tau) + sqrt(1.0 + tau * tau));
          c = 1.0 / sqrt(1.0 + tt * tt); s = tt * c;
        }
        cs_[t] = c; sn_[t] = s; ipp[t] = p; iqq[t] = q;
      }
      __syncthreads();
      if (t < 128) {   // column rotations of T and Ws
        int i = t & 15, mI = t >> 4;
        int p = ipp[mI], q = iqq[mI];
        double c = cs_[mI], s = sn_[mI];
        double u = shS[i * 17 + p], v = shS[i * 17 + q];
        shS[i * 17 + p] = c * u - s * v; shS[i * 17 + q] = s * u + c * v;
        double wu = Ws[i * 17 + p], wv = Ws[i * 17 + q];
        Ws[i * 17 + p] = c * wu - s * wv; Ws[i * 17 + q] = s * wu + c * wv;
      }
      __syncthreads();
      if (t < 128) {   // row rotations of T
        int j = t & 15, mI = t >> 4;
        int p = ipp[mI], q = iqq[mI];
        double c = cs_[mI], s = sn_[mI];
        double u = shS[p * 17 + j], v = shS[q * 17 + j];
        shS[p * 17 + j] = c * u - s * v; shS[q * 17 + j] = s * u + c * v;
      }
      __syncthreads();
    }
  }
  if (t == 0) {
    for (int i = 0; i < MSUB; ++i) { ev[i] = shS[i * 17 + i]; perm[i] = i; }
    for (int i = 0; i < MSUB; ++i) {
      int best = i;
      for (int j = i + 1; j < MSUB; ++j)
        if (ev[perm[j]] > ev[perm[best]]) best = j;
      int tp = perm[i]; perm[i] = perm[best]; perm[best] = tp;
    }
  }
  __syncthreads();
  // E = Q_orth * Ws (sorted); W1[i][c] = invsq_i * E ; W2[c][i] = E * sqrt(om_i)
  for (int idx = t; idx < K_ * MSUB; idx += 512) {
    int i = idx >> 4, c = idx & 15;
    int pc_ = perm[c];
    double e = 0.0;
    #pragma unroll
    for (int p = 0; p < MSUB; ++p) e += shZ[i * MSUB + p] * Ws[p * 17 + pc_];
    W1[i * MSUB + c] = (float)(inv_s[i] * e);
    W2[c * K_ + i]   = (float)(e / inv_s[i]);
  }
}

// ---------------- pc = x * W1 (f32), channel-major output ------------------
__global__ __launch_bounds__(256) void k_pc(const float* __restrict__ x,
                                            const float* __restrict__ W1,
                                            float* __restrict__ pc)
{
  __shared__ float xs[32][192];
  __shared__ float w1s[K_ * MSUB];
  int t = threadIdx.x;
  long n0 = (long)blockIdx.x * 32;
  for (int idx = t; idx < K_ * MSUB; idx += 256) w1s[idx] = W1[idx];
  for (int idx = t; idx < 32 * K_; idx += 256) {
    int row = idx / K_, col = idx - row * K_;
    xs[row][col] = x[(n0 + row) * K_ + col];
  }
  __syncthreads();
  int c = t & 15, nl = t >> 4;         // nl in [0,16)
  float a0 = 0.f, a1 = 0.f;
  for (int k = 0; k < K_; ++k) {
    float w = w1s[k * MSUB + c];
    a0 += xs[nl][k] * w;
    a1 += xs[nl + 16][k] * w;
  }
  __syncthreads();
  float* ts = &xs[0][0];               // reuse as 16x33 transpose buffer
  ts[c * 33 + nl]      = a0;
  ts[c * 33 + nl + 16] = a1;
  __syncthreads();
  for (int idx = t; idx < MSUB * 32; idx += 256) {
    int cc = idx >> 5, nn = idx & 31;
    pc[(size_t)cc * N_ + n0 + nn] = ts[cc * 33 + nn];
  }
}

// ---------------- DWT: vertical analysis pass ------------------------------
__global__ __launch_bounds__(256) void k_dwtv(const float* __restrict__ in,
                                              float* __restrict__ outv, int s)
{
  long gid = (long)blockIdx.x * 256 + threadIdx.x;
  int h = s >> 1;
  long per = (long)h * s;
  if (gid >= MSUB * per) return;
  int ch = (int)(gid / per);
  long rem = gid - (long)ch * per;
  int r = (int)(rem / s);
  int col = (int)(rem - (long)r * s);
  const float* cin = in + (long)ch * s * s;
  float la = 0.f, ld_ = 0.f;
  int base = 2 * r;
  #pragma unroll
  for (int l = 0; l < 10; ++l) {
    int rr_ = base + l; if (rr_ >= s) rr_ -= s;
    float v = cin[(long)rr_ * s + col];
    la += c_lo[l] * v; ld_ += c_hi[l] * v;
  }
  float* cout = outv + (long)ch * s * s;
  cout[(long)r * s + col] = la;
  cout[(long)(h + r) * s + col] = ld_;
}

// ---------------- DWT: horizontal analysis pass ----------------------------
__global__ __launch_bounds__(256) void k_dwth(const float* __restrict__ inv,
                                              float* __restrict__ llout,
                                              float* __restrict__ coef,
                                              int s, long offL, int last)
{
  long gid = (long)blockIdx.x * 256 + threadIdx.x;
  int h = s >> 1;
  long per = (long)s * h;
  if (gid >= MSUB * per) return;
  int ch = (int)(gid / per);
  long rem = gid - (long)ch * per;
  int r = (int)(rem / h);
  int mcol = (int)(rem - (long)r * h);
  const float* row = inv + (long)ch * s * s + (long)r * s;
  float lo = 0.f, hi = 0.f;
  int base = 2 * mcol;
  #pragma unroll
  for (int l = 0; l < 10; ++l) {
    int cc = base + l; if (cc >= s) cc -= s;
    float v = row[cc];
    lo += c_lo[l] * v; hi += c_hi[l] * v;
  }
  float* cslab = coef + (size_t)ch * N_ + offL;
  if (r < h) {
    llout[(size_t)ch * h * h + (long)r * h + mcol] = lo;
    if (last) coef[(size_t)ch * N_ + 147312 + (long)r * h + mcol] = lo;
    cslab[(long)r * h + mcol] = hi;
  } else {
    int rd = r - h;
    cslab[(long)h * h + (long)rd * h + mcol] = lo;
    cslab[(long)2 * h * h + (long)rd * h + mcol] = hi;
  }
}

// ---------------- SURE statistics per channel ------------------------------
__global__ __launch_bounds__(256) void k_stats(const float* __restrict__ coef,
                                               float* __restrict__ stats)
{
  int ch = blockIdx.x;
  int t = threadIdx.x;
  float T2[NT];
  {
    double stop = sqrt(log(147456.0));
    double step = stop / 14.0;
    for (int i = 0; i < NT; ++i) {
      double td = (i == 14) ? stop : (double)i * step;
      float tf = (float)td;
      T2[i] = tf * tf;
    }
  }
  float cn = 0.f, sm[NT], ct[NT];
  #pragma unroll
  for (int i = 0; i < NT; ++i) { sm[i] = 0.f; ct[i] = 0.f; }
  const float* base = coef + (size_t)ch * N_;
  for (int idx = t; idx < N_; idx += 256) {
    float v = base[idx];
    float v2 = v * v;
    cn += v2;
    #pragma unroll
    for (int i = 0; i < NT; ++i) {
      sm[i] += fminf(v2, T2[i]);
      ct[i] += (v2 > T2[i]) ? 1.0f : 0.0f;
    }
  }
  __shared__ float red[256];
  for (int a = 0; a < 31; ++a) {
    float val = (a == 0) ? cn : ((a < 16) ? sm[a - 1] : ct[a - 16]);
    red[t] = val;
    __syncthreads();
    for (int off = 128; off > 0; off >>= 1) {
      if (t < off) red[t] += red[t + off];
      __syncthreads();
    }
    if (t == 0) stats[ch * 31 + a] = red[0];
    __syncthreads();
  }
}

// ---------------- SURE scan + rank -----------------------------------------
__global__ void k_rank(const float* __restrict__ stats,
                       const float* __restrict__ normv, int* __restrict__ rankp)
{
  if (threadIdx.x != 0 || blockIdx.x != 0) return;
  float c_const = *normv - 28164096.0f;
  float acc[NT];
  for (int i = 0; i < NT; ++i) acc[i] = 0.f;
  float minsure[MSUB];
  for (int r = 0; r < MSUB; ++r) {
    float cn = stats[r * 31 + 0];
    float mn = 3.4e38f;
    for (int i = 0; i < NT; ++i) {
      float sure = stats[r * 31 + 1 + i] + 2.0f * stats[r * 31 + 16 + i] - cn;
      float s_r = acc[i] + sure + c_const;
      acc[i] = acc[i] + s_r;
      if (s_r < mn) mn = s_r;
    }
    minsure[r] = mn;
  }
  int rank = -1;
  for (int r = 2; r < MSUB; ++r) {
    if (minsure[r] > minsure[r - 1]) { rank = r; break; }
  }
  if (rank < 0) rank = MSUB - 1;
  *rankp = rank;
}

// ---------------- output: out = sqrt(omega) .* (pc[:, :rank] @ vh) ---------
__global__ __launch_bounds__(256) void k_out(const float* __restrict__ pc,
                                             const float* __restrict__ W2,
                                             const int* __restrict__ rankp,
                                             float* __restrict__ out)
{
  long gid = (long)blockIdx.x * 256 + threadIdx.x;
  int n = (int)(gid / K_);
  int j = (int)(gid - (long)n * K_);
  int rank = *rankp;
  float acc = 0.f;
  for (int c = 0; c < rank; ++c)
    acc += pc[(size_t)c * N_ + n] * W2[c * K_ + j];
  out[gid] = acc;
}

extern "C" void kernel_launch(void* const* d_in, const int* in_sizes, int n_in,
                              void* d_out, int out_size, void* d_ws, size_t ws_size,
                              hipStream_t stream)
{
  if (n_in < 1 || in_sizes[0] != N_ * K_) return;
  const float* x = (const float*)d_in[0];
  float* out = (float*)d_out;
  (void)out_size;

  char* w = (char*)d_ws;
  size_t off = 0;
  auto alloc = [&](size_t bytes) -> char* {
    char* p = w + off;
    off = (off + bytes + 255) & ~(size_t)255;
    return p;
  };
  double* m_    = (double*)alloc(K_ * 8);
  double* rrp   = (double*)alloc((size_t)K_ * K_ * 8);   // atomically-accumulated Gram
  double* rr    = (double*)alloc((size_t)K_ * LD * 8);
  double* invsq = (double*)alloc(K_ * 8);
  float*  sq32  = (float*)alloc(K_ * 4);
  float*  normv = (float*)alloc(256);
  float*  W1    = (float*)alloc((size_t)K_ * MSUB * 4);
  float*  W2    = (float*)alloc((size_t)MSUB * K_ * 4);
  float*  pc    = (float*)alloc((size_t)MSUB * N_ * 4);
  float*  tmpv  = (float*)alloc((size_t)MSUB * N_ * 4);
  float*  coef  = (float*)alloc((size_t)MSUB * N_ * 4);
  float*  curA  = (float*)alloc((size_t)MSUB * 192 * 192 * 4);
  float*  curB  = (float*)alloc((size_t)MSUB * 96 * 96 * 4);
  float*  stats = (float*)alloc((size_t)MSUB * 31 * 4);
  int*    rankp = (int*)alloc(256);
  if (off > ws_size) return;

  hipMemsetAsync(m_, 0, K_ * sizeof(double), stream);
  hipMemsetAsync(rrp, 0, (size_t)K_ * K_ * sizeof(double), stream);

  hipFuncSetAttribute(reinterpret_cast<const void*>(k_small2),
                      hipFuncAttributeMaxDynamicSharedMemorySize, SMEM_SZ);
  hipFuncSetAttribute(reinterpret_cast<const void*>(k_sub),
                      hipFuncAttributeMaxDynamicSharedMemorySize, SMEM2_SZ);

  k_colsum<<<N_ / 512, 256, 0, stream>>>(x, m_);
  k_rr<<<NPAIR * NSPLIT, 256, 0, stream>>>(x, rrp);
  k_reduce<<<(TRI_N + 255) / 256, 256, 0, stream>>>(rrp, rr);
  k_small2<<<1, 1024, SMEM_SZ, stream>>>(rr, m_, invsq, sq32, normv);
  k_sub<<<1, 512, SMEM2_SZ, stream>>>(rr, invsq, W1, W2);
  k_pc<<<N_ / 32, 256, 0, stream>>>(x, W1, pc);

  int   sizes[5] = {384, 192, 96, 48, 24};
  long  offs[5]  = {0, 110592, 138240, 145152, 146880};
  float* lls[5]  = {curA, curB, curA, curB, curA};
  const float* curin = pc;
  for (int lev = 0; lev < 5; ++lev) {
    int s = sizes[lev], h = s >> 1;
    long nth = (long)MSUB * h * s;
    k_dwtv<<<(int)((nth + 255) / 256), 256, 0, stream>>>(curin, tmpv, s);
    k_dwth<<<(int)((nth + 255) / 256), 256, 0, stream>>>(tmpv, lls[lev], coef,
                                                         s, offs[lev],
                                                         lev == 4 ? 1 : 0);
    curin = lls[lev];
  }

  k_stats<<<MSUB, 256, 0, stream>>>(coef, stats);
  k_rank<<<1, 64, 0, stream>>>(stats, normv, rankp);
  k_out<<<(N_ * K_) / 256, 256, 0, stream>>>(pc, W2, rankp, out);
}

// Round 4
// 1611.419 us; speedup vs baseline: 1.1950x; 1.0321x over previous
//
#include <hip/hip_runtime.h>
#include <math.h>

#define K_     191
#define LD     192
#define N_     147456
#define MSUB   16
#define NT     15
#define TRI_N  18336   // 191*192/2
#define SMEM_SZ ((TRI_N + 192 + 192 + 1056) * 8)
// k_sub dynamic LDS: 6880 doubles + 32 ints + 18336 floats
#define SMEM2_SZ (6880 * 8 + 32 * 4 + TRI_N * 4)

// k_rr geometry: 64-wide col blocks, 6 pairs, 128 K-splits
#define NPAIR  6
#define NSPLIT 128
#define CHUNK  (N_ / NSPLIT)   // 1152
#define RSTEP  32

// db5 decomposition filters (pywt convention), f32 as in reference
__constant__ float c_lo[10] = {
  0.003335725285001549f, -0.012580751999015526f, -0.006241490213011705f,
  0.07757149384006515f,  -0.03224486958502952f, -0.24229488706619015f,
  0.13842814590110342f,   0.7243085284385744f,   0.6038292697974729f,
  0.160102397974125f };
__constant__ float c_hi[10] = {
  0.160102397974125f,    -0.6038292697974729f,   0.7243085284385744f,
 -0.13842814590110342f,  -0.24229488706619015f,  0.03224486958502952f,
  0.07757149384006515f,   0.006241490213011705f,-0.012580751999015526f,
 -0.003335725285001549f };

// ---------------- column sums of x (f64), for the regression mean ----------
__global__ __launch_bounds__(256) void k_colsum(const float* __restrict__ x,
                                                double* __restrict__ m)
{
  int t = threadIdx.x;
  long base = (long)blockIdx.x * 512;
  if (t < K_) {
    double s = 0.0;
    const float* p = x + base * K_ + t;
    for (int r = 0; r < 512; ++r) s += (double)p[(long)r * K_];
    atomicAdd(&m[t], s);
  }
}

// ---------------- rr = x^T x, register-tiled VALU f64, split-K atomics -----
__global__ __launch_bounds__(256, 3) void k_rr(const float* __restrict__ x,
                                               double* __restrict__ rrg)
{
  __shared__ double Asd[RSTEP][64];
  __shared__ double Bsd[RSTEP][64];

  const int bid   = blockIdx.x;
  const int split = bid & (NSPLIT - 1);
  const int pair  = bid >> 7;
  const int BI[6] = {0, 0, 0, 1, 1, 2};
  const int BJ[6] = {0, 1, 2, 1, 2, 2};
  const int bi = BI[pair], bj = BJ[pair];
  const int ca = bi * 64, cb = bj * 64;

  const int t  = threadIdx.x;
  const int tx = t & 15, ty = t >> 4;
  const long n0 = (long)split * CHUNK;

  double acc[4][4];
  #pragma unroll
  for (int v = 0; v < 4; ++v)
    #pragma unroll
    for (int u = 0; u < 4; ++u) acc[v][u] = 0.0;

  for (int r0 = 0; r0 < CHUNK; r0 += RSTEP) {
    for (int s = t; s < RSTEP * 16; s += 256) {
      int row = s >> 4, g = s & 15;
      long gr = (n0 + r0 + row) * (long)K_;
      int c4a = ca + g * 4, c4b = cb + g * 4;
      #pragma unroll
      for (int e = 0; e < 4; ++e) {
        Asd[row][g * 4 + e] = (c4a + e < K_) ? (double)x[gr + c4a + e] : 0.0;
        Bsd[row][g * 4 + e] = (c4b + e < K_) ? (double)x[gr + c4b + e] : 0.0;
      }
    }
    __syncthreads();
    #pragma unroll 4
    for (int k = 0; k < RSTEP; ++k) {
      double a0 = Asd[k][ty],      a1 = Asd[k][ty + 16];
      double a2 = Asd[k][ty + 32], a3 = Asd[k][ty + 48];
      double b0 = Bsd[k][tx],      b1 = Bsd[k][tx + 16];
      double b2 = Bsd[k][tx + 32], b3 = Bsd[k][tx + 48];
      acc[0][0] += a0 * b0; acc[0][1] += a0 * b1; acc[0][2] += a0 * b2; acc[0][3] += a0 * b3;
      acc[1][0] += a1 * b0; acc[1][1] += a1 * b1; acc[1][2] += a1 * b2; acc[1][3] += a1 * b3;
      acc[2][0] += a2 * b0; acc[2][1] += a2 * b1; acc[2][2] += a2 * b2; acc[2][3] += a2 * b3;
      acc[3][0] += a3 * b0; acc[3][1] += a3 * b1; acc[3][2] += a3 * b2; acc[3][3] += a3 * b3;
    }
    __syncthreads();
  }

  #pragma unroll
  for (int v = 0; v < 4; ++v) {
    int mrow = ca + ty + 16 * v;
    #pragma unroll
    for (int u = 0; u < 4; ++u) {
      int ncol = cb + tx + 16 * u;
      if (mrow < K_ && ncol < K_)
        atomicAdd(&rrg[(size_t)mrow * K_ + ncol], acc[v][u]);
    }
  }
}

// ---------------- symmetrize accumulated upper -> rr (full square, LD) -----
__global__ __launch_bounds__(256) void k_reduce(const double* __restrict__ rrg,
                                                double* __restrict__ rr)
{
  int idx = blockIdx.x * 256 + threadIdx.x;   // packed lower-tri index
  if (idx >= TRI_N) return;
  int i = (int)((sqrtf(8.f * (float)idx + 1.f) - 1.f) * 0.5f);
  while ((i + 1) * (i + 2) / 2 <= idx) ++i;
  while (i * (i + 1) / 2 > idx) --i;
  int j = idx - (i * (i + 1)) / 2;            // j <= i
  double s = rrg[(size_t)j * K_ + i];         // valid entries live at (min,max)
  rr[i * LD + j] = s;
  rr[j * LD + i] = s;
}

// ---------------- LDS-resident small linear algebra ------------------------
// 512 threads (256-VGPR budget -> register arrays don't spill).
// Blocked Cholesky (reg diag factor + panel solve + 4x4 reg-tiled update),
// trtri with compile-time-unrolled batched loops (diag in registers,
// off-diag via zero-padded staging + in-wave shfl), unrolled finals.
__global__ __launch_bounds__(512) void k_small2(
    const double* __restrict__ rr, const double* __restrict__ m,
    double* __restrict__ invsq, float* __restrict__ sq32,
    float* __restrict__ normv)
{
  extern __shared__ double smem[];
  double* tri = smem;               // 18336
  double* m_s = smem + TRI_N;       // 192
  double* w1  = m_s + 192;          // 192
  double* tmp = w1 + 192;           // 32*33 = 1056 (multi-use scratch)
  const int t = threadIdx.x;

  if (t < K_) m_s[t] = m[t];
  for (int i = t >> 5; i < K_; i += 16) {
    int base = (i * (i + 1)) / 2;
    for (int j = t & 31; j <= i; j += 32) {
      double v = rr[i * LD + j];
      tri[base + j] = (i == j) ? v + 1e-6 : v;
    }
  }
  __syncthreads();

  // ---- blocked Cholesky, 6 panels of 32 columns ----
  for (int J = 0; J < 6; ++J) {
    const int j0 = J * 32;
    const int nb = (K_ - j0 < 32) ? (K_ - j0) : 32;   // 32 x5, then 31

    // Phase A: wave 0 factors the diag block in registers (lane = row).
    if (t < 64) {
      const int rl = t & 31;
      double a[32];
      #pragma unroll
      for (int c = 0; c < 32; ++c) {
        int i = j0 + rl;
        a[c] = (c <= rl && rl < nb) ? tri[(i * (i + 1)) / 2 + j0 + c] : 0.0;
      }
      #pragma unroll
      for (int k = 0; k < 32; ++k) {
        double akk = __shfl(a[k], k);
        double piv = sqrt(akk);
        double inv = 1.0 / piv;
        if (t == k) tmp[k] = inv;          // reciprocal diag for panel solve
        a[k] = (rl == k) ? piv : a[k] * inv;
        #pragma unroll
        for (int c = k + 1; c < 32; ++c) {
          double lck = __shfl(a[k], c);    // L[j0+c][j0+k]
          if (c <= rl) a[c] -= a[k] * lck;
        }
      }
      if (t < 32 && rl < nb) {
        int i = j0 + rl;
        int rb = (i * (i + 1)) / 2 + j0;
        #pragma unroll
        for (int c = 0; c < 32; ++c)
          if (c <= rl) tri[rb + c] = a[c];
      }
    }
    __syncthreads();

    // Phase B: panel solve, one row per thread.
    {
      int p = j0 + 32 + t;
      if (nb == 32 && p < K_) {
        int pb = (p * (p + 1)) / 2 + j0;
        double v[32];
        #pragma unroll
        for (int c = 0; c < 32; ++c) v[c] = tri[pb + c];
        #pragma unroll
        for (int c = 0; c < 32; ++c) {
          double s = v[c];
          #pragma unroll
          for (int q = 0; q < c; ++q) {
            int cc = j0 + c;
            s -= v[q] * tri[(cc * (cc + 1)) / 2 + j0 + q];
          }
          v[c] = s * tmp[c];
        }
        #pragma unroll
        for (int c = 0; c < 32; ++c) tri[pb + c] = v[c];
      }
    }
    __syncthreads();

    // Phase C: trailing update A -= L_panel L_panel^T, 4x4 register tiles.
    {
      int s0 = j0 + 32;
      int n = K_ - s0;
      if (n > 0) {
        int R4 = (n + 3) >> 2;
        int T4 = R4 * (R4 + 1) / 2;
        for (int tile = t; tile < T4; tile += 512) {
          int ti = (int)((sqrtf(8.f * (float)tile + 1.f) - 1.f) * 0.5f);
          while ((ti + 1) * (ti + 2) / 2 <= tile) ++ti;
          while (ti * (ti + 1) / 2 > tile) --ti;
          int tj = tile - ti * (ti + 1) / 2;
          int r0 = s0 + ti * 4, c0 = s0 + tj * 4;
          int rb[4], cb[4];
          #pragma unroll
          for (int u = 0; u < 4; ++u) {
            int r = (r0 + u < K_) ? r0 + u : K_ - 1;
            rb[u] = (r * (r + 1)) / 2;
            int c = (c0 + u < K_) ? c0 + u : K_ - 1;
            cb[u] = (c * (c + 1)) / 2;
          }
          double acc[4][4];
          #pragma unroll
          for (int u = 0; u < 4; ++u)
            #pragma unroll
            for (int v2 = 0; v2 < 4; ++v2) acc[u][v2] = 0.0;
          #pragma unroll 4
          for (int p = 0; p < 32; ++p) {
            double lr[4], lc[4];
            #pragma unroll
            for (int u = 0; u < 4; ++u) {
              lr[u] = tri[rb[u] + j0 + p];
              lc[u] = tri[cb[u] + j0 + p];
            }
            #pragma unroll
            for (int u = 0; u < 4; ++u)
              #pragma unroll
              for (int v2 = 0; v2 < 4; ++v2) acc[u][v2] += lr[u] * lc[v2];
          }
          #pragma unroll
          for (int u = 0; u < 4; ++u) {
            int r = r0 + u;
            if (r < K_) {
              #pragma unroll
              for (int v2 = 0; v2 < 4; ++v2) {
                int c = c0 + v2;
                if (c <= r) tri[rb[u] + c] -= acc[u][v2];
              }
            }
          }
        }
      }
    }
    __syncthreads();
  }

  // ---- trtri diag blocks: X_JJ = L_JJ^{-1}, column-per-thread registers ---
  for (int J = 0; J < 6; ++J) {
    const int j0 = J * 32;
    const int nb = (K_ - j0 < 32) ? (K_ - j0) : 32;
    if (t < 32) {
      int rd = (t < nb) ? j0 + t : K_ - 1;
      tmp[t] = 1.0 / tri[(rd * (rd + 1)) / 2 + rd];
    }
    __syncthreads();
    double xcol[32];
    if (t < 32) {
      const int c = t;
      #pragma unroll
      for (int r = 0; r < 32; ++r) {
        int rr_ = (j0 + r < K_) ? j0 + r : K_ - 1;
        int rb = (rr_ * (rr_ + 1)) / 2 + j0;
        double s = (r == c) ? 1.0 : 0.0;
        #pragma unroll
        for (int k = 0; k < 32; ++k)
          if (k < r) s -= tri[rb + k] * xcol[k];
        xcol[r] = s * tmp[r];
      }
    }
    __syncthreads();
    if (t < nb) {
      #pragma unroll
      for (int r = 0; r < 32; ++r) {
        int rr_ = j0 + r;
        if (r >= t && rr_ < K_)
          tri[(rr_ * (rr_ + 1)) / 2 + j0 + t] = xcol[r];
      }
    }
    __syncthreads();
  }

  // ---- trtri off-diag blocks: X_IJ = -X_II (acc), acc = sum L/X products --
  for (int J = 0; J < 5; ++J) {
    const int j0 = J * 32;
    // stage X_JJ zero-padded (upper part = 0) into tmp, 33-stride
    for (int idx = t; idx < 32 * 32; idx += 512) {
      int kk = idx >> 5, c = idx & 31;
      int row = j0 + kk;
      double v = 0.0;
      if (kk >= c && row < K_)
        v = tri[(row * (row + 1)) / 2 + j0 + c];
      tmp[kk * 33 + c] = v;
    }
    __syncthreads();
    for (int I = J + 1; I < 6; ++I) {
      const int i0 = I * 32;
      const int r = t & 31;
      #pragma unroll
      for (int half = 0; half < 2; ++half) {
        const int c = (t >> 5) + 16 * half;     // 0..31
        int ri = i0 + r;
        int ric = (ri < K_) ? ri : K_ - 1;
        int rb = (ric * (ric + 1)) / 2;
        double acc = 0.0;
        // k in [j0, j0+32): L[ri][k] * X_JJ[k][j0+c]  (zero-padded stage)
        #pragma unroll
        for (int kk = 0; kk < 32; ++kk)
          acc += tri[rb + j0 + kk] * tmp[kk * 33 + c];
        // k in [j0+32, i0): L[ri][k] * X[k][j0+c]
        for (int kb = j0 + 32; kb < i0; kb += 32) {
          #pragma unroll
          for (int kk = 0; kk < 32; ++kk) {
            int k = kb + kk;
            acc += tri[rb + k] * tri[(k * (k + 1)) / 2 + j0 + c];
          }
        }
        // out = -sum_{k<=r} X_II[r][k] * acc[k][c]  via in-wave shfl
        double out = 0.0;
        #pragma unroll
        for (int k = 0; k < 32; ++k) {
          double av = __shfl(acc, (t & 32) | k, 64);
          double xv = (k <= r) ? tri[rb + i0 + k] : 0.0;
          out -= xv * av;
        }
        if (ri < K_)
          tri[rb + j0 + c] = out;
      }
      __syncthreads();
    }
  }

  if (t < K_) {
    int r = t, rb = (r * (r + 1)) / 2;
    double s = 0.0;
    #pragma unroll 8
    for (int p = 0; p <= r; ++p) s += tri[rb + p] * m_s[p];
    w1[r] = s;
  }
  __syncthreads();
  if (t < K_) {
    int i = t;
    double s2 = 0.0, s1 = 0.0;
    #pragma unroll 8
    for (int r = i; r < K_; ++r) {
      double xv = tri[(r * (r + 1)) / 2 + i];
      s2 += xv * xv;
      s1 += xv * w1[r];
    }
    double dii = s2;
    double q = 1.0 / dii;
    double sm_ = s1 / dii;
    double var = (q - sm_ * sm_ / (double)N_) / (double)(N_ - 1);
    double t1 = sqrt(var) + 1e-30;
    double om = t1 * t1;
    invsq[i] = 1.0 / sqrt(om);
    sq32[i] = sqrtf((float)om);
    tmp[i] = rr[i * LD + i] / om;
  }
  __syncthreads();
  if (t < 64) {
    double s = 0.0;
    for (int i = t; i < K_; i += 64) s += tmp[i];
    #pragma unroll
    for (int off = 32; off > 0; off >>= 1) s += __shfl_down(s, off);
    if (t == 0) *normv = (float)s;
  }
}

// ---------------- CholQR helper (operates on shQ K_ x MSUB, shS MSUB x 17) -
__device__ __forceinline__ void cholqr(double* shQ, double* shS, int t)
{
  // S = Q^T Q
  if (t < MSUB * MSUB) {
    int a = t & (MSUB - 1), b = t >> 4;
    double s = 0.0;
    for (int r = 0; r < K_; ++r) s += shQ[r * MSUB + a] * shQ[r * MSUB + b];
    shS[b * 17 + a] = s;
  }
  __syncthreads();
  // Cholesky 16x16 (lower)
  for (int k = 0; k < MSUB; ++k) {
    if (t == 0) shS[k * 17 + k] = sqrt(shS[k * 17 + k]);
    __syncthreads();
    if (t > k && t < MSUB) shS[t * 17 + k] /= shS[k * 17 + k];
    __syncthreads();
    if (t < MSUB * MSUB) {
      int r = t & (MSUB - 1), c = t >> 4;
      if (c > k && r >= c) shS[r * 17 + c] -= shS[r * 17 + k] * shS[c * 17 + k];
    }
    __syncthreads();
  }
  // rows solve: Qnew L^T = Qold
  if (t < K_) {
    double q[MSUB];
    #pragma unroll
    for (int c = 0; c < MSUB; ++c) {
      double v = shQ[t * MSUB + c];
      for (int p = 0; p < c; ++p) v -= q[p] * shS[c * 17 + p];
      q[c] = v / shS[c * 17 + c];
    }
    #pragma unroll
    for (int c = 0; c < MSUB; ++c) shQ[t * MSUB + c] = q[c];
  }
  __syncthreads();
}

// ---------------- one-block subspace iteration, top-16 eigenpairs ----------
__global__ __launch_bounds__(512) void k_sub(
    const double* __restrict__ rr, const double* __restrict__ invsq,
    float* __restrict__ W1, float* __restrict__ W2)
{
  extern __shared__ double dsm[];
  double* shQ  = dsm;                 // 3056
  double* shZ  = shQ + 3056;          // 3056
  double* shS  = shZ + 3056;          // 272 (16*17)
  double* Ws   = shS + 272;           // 272
  double* inv_s= Ws + 272;            // 192
  double* ev   = inv_s + 192;         // 16
  double* cs_  = ev + 16;             // 8
  double* sn_  = cs_ + 8;             // 8
  int* ipp  = (int*)(sn_ + 8);        // 8
  int* iqq  = ipp + 8;                // 8
  int* perm = iqq + 8;                // 16
  float* tri = (float*)(perm + 16);   // 18336
  const int t = threadIdx.x;

  if (t < K_) inv_s[t] = invsq[t];
  __syncthreads();
  // stage G lower triangle (f32): G_ij = rr_ij * invsq_i * invsq_j
  for (int i = t >> 4; i < K_; i += 32) {
    int base = (i * (i + 1)) / 2;
    double di = inv_s[i];
    for (int j = t & 15; j <= i; j += 16)
      tri[base + j] = (float)(rr[i * LD + j] * di * inv_s[j]);
  }
  __syncthreads();

  // init Q = G[:, 0:16]
  for (int idx = t; idx < K_ * MSUB; idx += 512) {
    int i = idx >> 4, c = idx & 15;
    float g = (i >= c) ? tri[(i * (i + 1)) / 2 + c] : tri[(c * (c + 1)) / 2 + i];
    shQ[idx] = (double)g;
  }
  __syncthreads();

  cholqr(shQ, shS, t);
  for (int it = 0; it < 4; ++it) {
    // copy Q -> Z
    for (int idx = t; idx < K_ * MSUB; idx += 512) shZ[idx] = shQ[idx];
    __syncthreads();
    // Q = G * Z   (triangular-packed G)
    for (int idx = t; idx < K_ * MSUB; idx += 512) {
      int i = idx >> 4, c = idx & 15;
      double s = 0.0;
      int rb = (i * (i + 1)) >> 1;
      for (int k = 0; k <= i; ++k) s += (double)tri[rb + k] * shZ[k * MSUB + c];
      int kk = ((i + 1) * (i + 2)) >> 1;
      for (int k = i + 1; k < K_; ++k) { s += (double)tri[kk + i] * shZ[k * MSUB + c]; kk += k + 1; }
      shQ[idx] = s;
    }
    __syncthreads();
    if (it < 3) cholqr(shQ, shS, t);
  }
  // here: shZ = Q_orth, shQ = G*Q_orth.  T = Z^T Q  -> shS
  if (t < MSUB * MSUB) {
    int a = t & 15, b = t >> 4;
    double s = 0.0;
    for (int r = 0; r < K_; ++r) s += shZ[r * MSUB + b] * shQ[r * MSUB + a];
    shS[b * 17 + a] = s;
  }
  // init Ws = I
  if (t < MSUB * 17) Ws[t] = 0.0;
  __syncthreads();
  if (t < MSUB) Ws[t * 17 + t] = 1.0;
  __syncthreads();
  // Jacobi eigensolve of 16x16 T
  for (int sweep = 0; sweep < 6; ++sweep) {
    for (int round = 0; round < 15; ++round) {
      if (t < 8) {
        int ia = (t == 0) ? 0 : (1 + ((t - 1 + round) % 15));
        int ib = 1 + ((14 - t + round) % 15);
        int p = ia < ib ? ia : ib;
        int q = ia < ib ? ib : ia;
        double app = shS[p * 17 + p], aqq = shS[q * 17 + q], apq = shS[p * 17 + q];
        double c = 1.0, s = 0.0;
        if (fabs(apq) > 1e-30 * (fabs(app) + fabs(aqq)) && apq != 0.0) {
          double tau = (aqq - app) / (2.0 * apq);
          double tt = (tau >= 0.0 ? 1.0 : -1.0) / (fabs(tau) + sqrt(1.0 + tau * tau));
          c = 1.0 / sqrt(1.0 + tt * tt); s = tt * c;
        }
        cs_[t] = c; sn_[t] = s; ipp[t] = p; iqq[t] = q;
      }
      __syncthreads();
      if (t < 128) {   // column rotations of T and Ws
        int i = t & 15, mI = t >> 4;
        int p = ipp[mI], q = iqq[mI];
        double c = cs_[mI], s = sn_[mI];
        double u = shS[i * 17 + p], v = shS[i * 17 + q];
        shS[i * 17 + p] = c * u - s * v; shS[i * 17 + q] = s * u + c * v;
        double wu = Ws[i * 17 + p], wv = Ws[i * 17 + q];
        Ws[i * 17 + p] = c * wu - s * wv; Ws[i * 17 + q] = s * wu + c * wv;
      }
      __syncthreads();
      if (t < 128) {   // row rotations of T
        int j = t & 15, mI = t >> 4;
        int p = ipp[mI], q = iqq[mI];
        double c = cs_[mI], s = sn_[mI];
        double u = shS[p * 17 + j], v = shS[q * 17 + j];
        shS[p * 17 + j] = c * u - s * v; shS[q * 17 + j] = s * u + c * v;
      }
      __syncthreads();
    }
  }
  if (t == 0) {
    for (int i = 0; i < MSUB; ++i) { ev[i] = shS[i * 17 + i]; perm[i] = i; }
    for (int i = 0; i < MSUB; ++i) {
      int best = i;
      for (int j = i + 1; j < MSUB; ++j)
        if (ev[perm[j]] > ev[perm[best]]) best = j;
      int tp = perm[i]; perm[i] = perm[best]; perm[best] = tp;
    }
  }
  __syncthreads();
  // E = Q_orth * Ws (sorted); W1[i][c] = invsq_i * E ; W2[c][i] = E * sqrt(om_i)
  for (int idx = t; idx < K_ * MSUB; idx += 512) {
    int i = idx >> 4, c = idx & 15;
    int pc_ = perm[c];
    double e = 0.0;
    #pragma unroll
    for (int p = 0; p < MSUB; ++p) e += shZ[i * MSUB + p] * Ws[p * 17 + pc_];
    W1[i * MSUB + c] = (float)(inv_s[i] * e);
    W2[c * K_ + i]   = (float)(e / inv_s[i]);
  }
}

// ---------------- pc = x * W1 (f32), channel-major output ------------------
__global__ __launch_bounds__(256) void k_pc(const float* __restrict__ x,
                                            const float* __restrict__ W1,
                                            float* __restrict__ pc)
{
  __shared__ float xs[32][192];
  __shared__ float w1s[K_ * MSUB];
  int t = threadIdx.x;
  long n0 = (long)blockIdx.x * 32;
  for (int idx = t; idx < K_ * MSUB; idx += 256) w1s[idx] = W1[idx];
  for (int idx = t; idx < 32 * K_; idx += 256) {
    int row = idx / K_, col = idx - row * K_;
    xs[row][col] = x[(n0 + row) * K_ + col];
  }
  __syncthreads();
  int c = t & 15, nl = t >> 4;         // nl in [0,16)
  float a0 = 0.f, a1 = 0.f;
  for (int k = 0; k < K_; ++k) {
    float w = w1s[k * MSUB + c];
    a0 += xs[nl][k] * w;
    a1 += xs[nl + 16][k] * w;
  }
  __syncthreads();
  float* ts = &xs[0][0];               // reuse as 16x33 transpose buffer
  ts[c * 33 + nl]      = a0;
  ts[c * 33 + nl + 16] = a1;
  __syncthreads();
  for (int idx = t; idx < MSUB * 32; idx += 256) {
    int cc = idx >> 5, nn = idx & 31;
    pc[(size_t)cc * N_ + n0 + nn] = ts[cc * 33 + nn];
  }
}

// ---------------- DWT: vertical analysis pass ------------------------------
__global__ __launch_bounds__(256) void k_dwtv(const float* __restrict__ in,
                                              float* __restrict__ outv, int s)
{
  long gid = (long)blockIdx.x * 256 + threadIdx.x;
  int h = s >> 1;
  long per = (long)h * s;
  if (gid >= MSUB * per) return;
  int ch = (int)(gid / per);
  long rem = gid - (long)ch * per;
  int r = (int)(rem / s);
  int col = (int)(rem - (long)r * s);
  const float* cin = in + (long)ch * s * s;
  float la = 0.f, ld_ = 0.f;
  int base = 2 * r;
  #pragma unroll
  for (int l = 0; l < 10; ++l) {
    int rr_ = base + l; if (rr_ >= s) rr_ -= s;
    float v = cin[(long)rr_ * s + col];
    la += c_lo[l] * v; ld_ += c_hi[l] * v;
  }
  float* cout = outv + (long)ch * s * s;
  cout[(long)r * s + col] = la;
  cout[(long)(h + r) * s + col] = ld_;
}

// ---------------- DWT: horizontal analysis pass ----------------------------
__global__ __launch_bounds__(256) void k_dwth(const float* __restrict__ inv,
                                              float* __restrict__ llout,
                                              float* __restrict__ coef,
                                              int s, long offL, int last)
{
  long gid = (long)blockIdx.x * 256 + threadIdx.x;
  int h = s >> 1;
  long per = (long)s * h;
  if (gid >= MSUB * per) return;
  int ch = (int)(gid / per);
  long rem = gid - (long)ch * per;
  int r = (int)(rem / h);
  int mcol = (int)(rem - (long)r * h);
  const float* row = inv + (long)ch * s * s + (long)r * s;
  float lo = 0.f, hi = 0.f;
  int base = 2 * mcol;
  #pragma unroll
  for (int l = 0; l < 10; ++l) {
    int cc = base + l; if (cc >= s) cc -= s;
    float v = row[cc];
    lo += c_lo[l] * v; hi += c_hi[l] * v;
  }
  float* cslab = coef + (size_t)ch * N_ + offL;
  if (r < h) {
    llout[(size_t)ch * h * h + (long)r * h + mcol] = lo;
    if (last) coef[(size_t)ch * N_ + 147312 + (long)r * h + mcol] = lo;
    cslab[(long)r * h + mcol] = hi;
  } else {
    int rd = r - h;
    cslab[(long)h * h + (long)rd * h + mcol] = lo;
    cslab[(long)2 * h * h + (long)rd * h + mcol] = hi;
  }
}

// ---------------- SURE statistics per channel ------------------------------
__global__ __launch_bounds__(256) void k_stats(const float* __restrict__ coef,
                                               float* __restrict__ stats)
{
  int ch = blockIdx.x;
  int t = threadIdx.x;
  float T2[NT];
  {
    double stop = sqrt(log(147456.0));
    double step = stop / 14.0;
    for (int i = 0; i < NT; ++i) {
      double td = (i == 14) ? stop : (double)i * step;
      float tf = (float)td;
      T2[i] = tf * tf;
    }
  }
  float cn = 0.f, sm[NT], ct[NT];
  #pragma unroll
  for (int i = 0; i < NT; ++i) { sm[i] = 0.f; ct[i] = 0.f; }
  const float* base = coef + (size_t)ch * N_;
  for (int idx = t; idx < N_; idx += 256) {
    float v = base[idx];
    float v2 = v * v;
    cn += v2;
    #pragma unroll
    for (int i = 0; i < NT; ++i) {
      sm[i] += fminf(v2, T2[i]);
      ct[i] += (v2 > T2[i]) ? 1.0f : 0.0f;
    }
  }
  __shared__ float red[256];
  for (int a = 0; a < 31; ++a) {
    float val = (a == 0) ? cn : ((a < 16) ? sm[a - 1] : ct[a - 16]);
    red[t] = val;
    __syncthreads();
    for (int off = 128; off > 0; off >>= 1) {
      if (t < off) red[t] += red[t + off];
      __syncthreads();
    }
    if (t == 0) stats[ch * 31 + a] = red[0];
    __syncthreads();
  }
}

// ---------------- SURE scan + rank -----------------------------------------
__global__ void k_rank(const float* __restrict__ stats,
                       const float* __restrict__ normv, int* __restrict__ rankp)
{
  if (threadIdx.x != 0 || blockIdx.x != 0) return;
  float c_const = *normv - 28164096.0f;
  float acc[NT];
  for (int i = 0; i < NT; ++i) acc[i] = 0.f;
  float minsure[MSUB];
  for (int r = 0; r < MSUB; ++r) {
    float cn = stats[r * 31 + 0];
    float mn = 3.4e38f;
    for (int i = 0; i < NT; ++i) {
      float sure = stats[r * 31 + 1 + i] + 2.0f * stats[r * 31 + 16 + i] - cn;
      float s_r = acc[i] + sure + c_const;
      acc[i] = acc[i] + s_r;
      if (s_r < mn) mn = s_r;
    }
    minsure[r] = mn;
  }
  int rank = -1;
  for (int r = 2; r < MSUB; ++r) {
    if (minsure[r] > minsure[r - 1]) { rank = r; break; }
  }
  if (rank < 0) rank = MSUB - 1;
  *rankp = rank;
}

// ---------------- output: out = sqrt(omega) .* (pc[:, :rank] @ vh) ---------
__global__ __launch_bounds__(256) void k_out(const float* __restrict__ pc,
                                             const float* __restrict__ W2,
                                             const int* __restrict__ rankp,
                                             float* __restrict__ out)
{
  long gid = (long)blockIdx.x * 256 + threadIdx.x;
  int n = (int)(gid / K_);
  int j = (int)(gid - (long)n * K_);
  int rank = *rankp;
  float acc = 0.f;
  for (int c = 0; c < rank; ++c)
    acc += pc[(size_t)c * N_ + n] * W2[c * K_ + j];
  out[gid] = acc;
}

extern "C" void kernel_launch(void* const* d_in, const int* in_sizes, int n_in,
                              void* d_out, int out_size, void* d_ws, size_t ws_size,
                              hipStream_t stream)
{
  if (n_in < 1 || in_sizes[0] != N_ * K_) return;
  const float* x = (const float*)d_in[0];
  float* out = (float*)d_out;
  (void)out_size;

  char* w = (char*)d_ws;
  size_t off = 0;
  auto alloc = [&](size_t bytes) -> char* {
    char* p = w + off;
    off = (off + bytes + 255) & ~(size_t)255;
    return p;
  };
  double* m_    = (double*)alloc(K_ * 8);
  double* rrp   = (double*)alloc((size_t)K_ * K_ * 8);   // atomically-accumulated Gram
  double* rr    = (double*)alloc((size_t)K_ * LD * 8);
  double* invsq = (double*)alloc(K_ * 8);
  float*  sq32  = (float*)alloc(K_ * 4);
  float*  normv = (float*)alloc(256);
  float*  W1    = (float*)alloc((size_t)K_ * MSUB * 4);
  float*  W2    = (float*)alloc((size_t)MSUB * K_ * 4);
  float*  pc    = (float*)alloc((size_t)MSUB * N_ * 4);
  float*  tmpv  = (float*)alloc((size_t)MSUB * N_ * 4);
  float*  coef  = (float*)alloc((size_t)MSUB * N_ * 4);
  float*  curA  = (float*)alloc((size_t)MSUB * 192 * 192 * 4);
  float*  curB  = (float*)alloc((size_t)MSUB * 96 * 96 * 4);
  float*  stats = (float*)alloc((size_t)MSUB * 31 * 4);
  int*    rankp = (int*)alloc(256);
  if (off > ws_size) return;

  hipMemsetAsync(m_, 0, K_ * sizeof(double), stream);
  hipMemsetAsync(rrp, 0, (size_t)K_ * K_ * sizeof(double), stream);

  hipFuncSetAttribute(reinterpret_cast<const void*>(k_small2),
                      hipFuncAttributeMaxDynamicSharedMemorySize, SMEM_SZ);
  hipFuncSetAttribute(reinterpret_cast<const void*>(k_sub),
                      hipFuncAttributeMaxDynamicSharedMemorySize, SMEM2_SZ);

  k_colsum<<<N_ / 512, 256, 0, stream>>>(x, m_);
  k_rr<<<NPAIR * NSPLIT, 256, 0, stream>>>(x, rrp);
  k_reduce<<<(TRI_N + 255) / 256, 256, 0, stream>>>(rrp, rr);
  k_small2<<<1, 512, SMEM_SZ, stream>>>(rr, m_, invsq, sq32, normv);
  k_sub<<<1, 512, SMEM2_SZ, stream>>>(rr, invsq, W1, W2);
  k_pc<<<N_ / 32, 256, 0, stream>>>(x, W1, pc);

  int   sizes[5] = {384, 192, 96, 48, 24};
  long  offs[5]  = {0, 110592, 138240, 145152, 146880};
  float* lls[5]  = {curA, curB, curA, curB, curA};
  const float* curin = pc;
  for (int lev = 0; lev < 5; ++lev) {
    int s = sizes[lev], h = s >> 1;
    long nth = (long)MSUB * h * s;
    k_dwtv<<<(int)((nth + 255) / 256), 256, 0, stream>>>(curin, tmpv, s);
    k_dwth<<<(int)((nth + 255) / 256), 256, 0, stream>>>(tmpv, lls[lev], coef,
                                                         s, offs[lev],
                                                         lev == 4 ? 1 : 0);
    curin = lls[lev];
  }

  k_stats<<<MSUB, 256, 0, stream>>>(coef, stats);
  k_rank<<<1, 64, 0, stream>>>(stats, normv, rankp);
  k_out<<<(N_ * K_) / 256, 256, 0, stream>>>(pc, W2, rankp, out);
}